// Round 4
// baseline (315.361 us; speedup 1.0000x reference)
//
#include <hip/hip_runtime.h>
#include <math.h>

typedef float fx4 __attribute__((ext_vector_type(4)));

#define TM    32            // rows per block (4 waves x 8 rows)
#define KC    32            // K chunk staged in LDS
#define DDIM  2048
#define ENUM  64
#define NC    (DDIM / KC)   // 64 chunks

// Layout: ws[buf][col][k-chunk], col 0..63 = Wg rows, 64..127 = Wn rows.
// 16B groups XOR-swizzled by (col&7) so wave-wide b128 reads/writes spread
// over all 32 banks (plain [col][32] layout puts all 64 lanes on one bank quad).

__global__ __launch_bounds__(256, 2)
void noisy_topk_kernel(const float* __restrict__ x,
                       const float* __restrict__ eps,
                       const float* __restrict__ Wg,
                       const float* __restrict__ gb,
                       const float* __restrict__ Wn,
                       const float* __restrict__ nb,
                       float* __restrict__ out)
{
    __shared__ float ws[2][128][KC];   // 32 KB

    const int tid  = threadIdx.x;
    const int lane = tid & 63;
    // wave id, forced wave-uniform so x addresses become scalar
    const int uwid = __builtin_amdgcn_readfirstlane(tid >> 6);
    const int row0 = blockIdx.x * TM + uwid * 8;     // wave's 8 rows (uniform)
    const float* __restrict__ xb = x + (size_t)row0 * DDIM;

    // ---- W staging mapping: thread -> (col, half) ----
    const int scol = tid & 127;
    const int sh   = tid >> 7;                       // 0/1: k-halves of chunk
    const float* wsp = ((scol < ENUM) ? (Wg + (size_t)scol * DDIM)
                                      : (Wn + (size_t)(scol - ENUM) * DDIM))
                       + sh * 16;
    const int ssw = scol & 7;                        // staging swizzle key

    // ---- per-lane compute pointers ----
    const int sw = lane & 7;                         // read swizzle key

    float acc[8][2];
    #pragma unroll
    for (int r = 0; r < 8; ++r) { acc[r][0] = 0.f; acc[r][1] = 0.f; }

    fx4 xbuf[2][8];
    fx4 wgbuf[2], wnbuf[2];
    fx4 st[4];

    // ---- prologue: stage W chunk 0, load W chunk 1 regs, x group 0 ----
    #pragma unroll
    for (int j = 0; j < 4; ++j) {
        fx4 v = *(const fx4*)(wsp + j * 4);
        *(fx4*)&ws[0][scol][((sh * 4 + j) ^ ssw) << 2] = v;
    }
    #pragma unroll
    for (int j = 0; j < 4; ++j)
        st[j] = *(const fx4*)(wsp + KC + j * 4);
    #pragma unroll
    for (int r = 0; r < 8; ++r)
        xbuf[0][r] = *(const fx4*)(xb + r * DDIM + 0);
    __syncthreads();

    for (int c = 0; c < NC; ++c) {
        const int cur = c & 1;
        const int nxt = cur ^ 1;

        // write chunk c+1 (in st regs) into other buffer
        if (c + 1 < NC) {
            #pragma unroll
            for (int j = 0; j < 4; ++j)
                *(fx4*)&ws[nxt][scol][((sh * 4 + j) ^ ssw) << 2] = st[j];
        }
        // load chunk c+2 into st regs (returns during compute)
        if (c + 2 < NC) {
            const int ko = (c + 2) * KC;
            #pragma unroll
            for (int j = 0; j < 4; ++j)
                st[j] = *(const fx4*)(wsp + ko + j * 4);
        }

        // ---- compute chunk c: 8 groups of 4 k ----
        const float* wgp = &ws[cur][lane][0];
        const float* wnp = &ws[cur][ENUM + lane][0];
        wgbuf[0] = *(const fx4*)(wgp + ((0 ^ sw) << 2));
        wnbuf[0] = *(const fx4*)(wnp + ((0 ^ sw) << 2));

        #pragma unroll
        for (int g = 0; g < 8; ++g) {
            const int pc = g & 1, pn = pc ^ 1;
            if (g < 7) {
                wgbuf[pn] = *(const fx4*)(wgp + (((g + 1) ^ sw) << 2));
                wnbuf[pn] = *(const fx4*)(wnp + (((g + 1) ^ sw) << 2));
            }
            {   // prefetch next x group (wraps harmlessly at end)
                const int kn = (c * KC + (g + 1) * 4) & (DDIM - 1);
                #pragma unroll
                for (int r = 0; r < 8; ++r)
                    xbuf[pn][r] = *(const fx4*)(xb + r * DDIM + kn);
            }
            #pragma unroll
            for (int kk = 0; kk < 4; ++kk)
                #pragma unroll
                for (int r = 0; r < 8; ++r) {
                    acc[r][0] = fmaf(xbuf[pc][r][kk], wgbuf[pc][kk], acc[r][0]);
                    acc[r][1] = fmaf(xbuf[pc][r][kk], wnbuf[pc][kk], acc[r][1]);
                }
        }
        __syncthreads();
    }

    // ---- epilogue: biases, softplus, per-row top-2 butterfly, softmax, store ----
    const float gbias = gb[lane];
    const float nbias = nb[lane];

    #pragma unroll
    for (int r = 0; r < 8; ++r) {
        const size_t rowoff = (size_t)(row0 + r) * ENUM + lane;
        float gate = acc[r][0] + gbias;
        float nz   = acc[r][1] + nbias;
        float sp   = fmaxf(nz, 0.f) + log1pf(expf(-fabsf(nz)));
        float ev   = eps[rowoff];
        float h    = gate + ev * sp;

        float v1 = h, v2 = -INFINITY;
        int   i1 = lane, i2 = -1;
        #pragma unroll
        for (int off = 32; off > 0; off >>= 1) {
            float o1 = __shfl_xor(v1, off);
            int  oi1 = __shfl_xor(i1, off);
            float o2 = __shfl_xor(v2, off);
            int  oi2 = __shfl_xor(i2, off);
            if (o1 > v1) {
                if (o2 > v1) { v2 = o2; i2 = oi2; }
                else         { v2 = v1; i2 = i1;  }
                v1 = o1; i1 = oi1;
            } else if (o1 > v2) {
                v2 = o1; i2 = oi1;
            }
        }
        float e2 = expf(v2 - v1);
        float p1 = 1.f / (1.f + e2);
        float p2 = e2 * p1;
        out[rowoff] = (lane == i1) ? p1 : ((lane == i2) ? p2 : 0.f);
    }
}

extern "C" void kernel_launch(void* const* d_in, const int* in_sizes, int n_in,
                              void* d_out, int out_size, void* d_ws, size_t ws_size,
                              hipStream_t stream) {
    const float* x   = (const float*)d_in[0];
    const float* eps = (const float*)d_in[1];
    const float* Wg  = (const float*)d_in[2];
    const float* gbp = (const float*)d_in[3];
    const float* Wn  = (const float*)d_in[4];
    const float* nbp = (const float*)d_in[5];
    float* out = (float*)d_out;

    const int M = in_sizes[0] / DDIM;    // B*T = 16384
    dim3 grid(M / TM), block(256);
    hipLaunchKernelGGL(noisy_topk_kernel, grid, block, 0, stream,
                       x, eps, Wg, gbp, Wn, nbp, out);
}

// Round 5
// 160.487 us; speedup vs baseline: 1.9650x; 1.9650x over previous
//
#include <hip/hip_runtime.h>
#include <math.h>

typedef float fx4 __attribute__((ext_vector_type(4)));

#define TM    64            // rows per block
#define KC    32            // K chunk staged in LDS (8 groups of 4)
#define DDIM  2048
#define ENUM  64
#define NC    (DDIM / KC)   // 64 chunks

// xs: [row][k], 16B k-groups XOR-swizzled by (row&7)  -> writes 2-way (free),
//     reads broadcast (32 lanes same addr), conflict-free.
// ws: [col][k], 16B k-groups XOR-swizzled by ((col&63)>>1)&7 -> reads spread
//     8 perms x 4 lanes = 512B data-volume floor; writes 8 perms = 1024B floor.

__global__ __launch_bounds__(256, 1)
void noisy_topk_kernel(const float* __restrict__ x,
                       const float* __restrict__ eps,
                       const float* __restrict__ Wg,
                       const float* __restrict__ gb,
                       const float* __restrict__ Wn,
                       const float* __restrict__ nb,
                       float* __restrict__ out)
{
    __shared__ float xs[2][TM][KC];    // 16 KB
    __shared__ float ws[2][128][KC];   // 32 KB

    const int tid  = threadIdx.x;
    const int lane = tid & 63;
    const int wid  = tid >> 6;
    const int row0 = blockIdx.x * TM;

    // ---- compute mapping: lane -> (rg, cg) ----
    const int cg  = lane & 31;                 // col-pair id 0..31
    const int rg  = wid * 2 + (lane >> 5);     // 0..7 -> rows rg*8..rg*8+7
    const int key = cg & 7;                    // ws read swizzle key

    // owned cols: gate {2cg, 2cg+1}, noise {64+2cg, 65+2cg}
    const int cb0 = (2 * cg) * KC;
    const int cb1 = (2 * cg + 1) * KC;
    const int cb2 = (64 + 2 * cg) * KC;
    const int cb3 = (65 + 2 * cg) * KC;

    float acc[8][4];
    #pragma unroll
    for (int r = 0; r < 8; ++r)
        #pragma unroll
        for (int cc = 0; cc < 4; ++cc) acc[r][cc] = 0.f;

    // ---- staging maps ----
    const int srow = tid >> 2, sj = tid & 3;   // x: 4 threads/row, 2 fx4 each
    const int skx  = srow & 7;
    const float* xp = x + (size_t)(row0 + srow) * DDIM + sj * 4;

    const int scol = tid >> 1, sh = tid & 1;   // W: 2 threads/col, 4 fx4 each
    const int skey = ((scol & 63) >> 1) & 7;
    const float* wsp = ((scol < ENUM) ? (Wg + (size_t)scol * DDIM)
                                      : (Wn + (size_t)(scol - ENUM) * DDIM))
                       + sh * 16;

    // ---- prologue: stage chunk 0, preload chunk 1 into regs ----
    {
        fx4 a0 = *(const fx4*)(xp);
        fx4 a1 = *(const fx4*)(xp + 16);
        *(fx4*)&xs[0][srow][((sj     ^ skx) << 2)] = a0;
        *(fx4*)&xs[0][srow][(((sj+4) ^ skx) << 2)] = a1;
        #pragma unroll
        for (int j = 0; j < 4; ++j) {
            fx4 v = *(const fx4*)(wsp + j * 4);
            *(fx4*)&ws[0][scol][(((sh*4 + j) ^ skey) << 2)] = v;
        }
    }
    fx4 xst0 = *(const fx4*)(xp + KC);
    fx4 xst1 = *(const fx4*)(xp + KC + 16);
    fx4 wst[4];
    #pragma unroll
    for (int j = 0; j < 4; ++j) wst[j] = *(const fx4*)(wsp + KC + j * 4);
    __syncthreads();

    for (int c = 0; c < NC; ++c) {
        const int cur = c & 1;
        const int nxt = cur ^ 1;

        // stage chunk c+1 from regs
        if (c + 1 < NC) {
            *(fx4*)&xs[nxt][srow][((sj     ^ skx) << 2)] = xst0;
            *(fx4*)&xs[nxt][srow][(((sj+4) ^ skx) << 2)] = xst1;
            #pragma unroll
            for (int j = 0; j < 4; ++j)
                *(fx4*)&ws[nxt][scol][(((sh*4 + j) ^ skey) << 2)] = wst[j];
        }
        // preload chunk c+2 (latency hidden under compute)
        if (c + 2 < NC) {
            const int ko = (c + 2) * KC;
            xst0 = *(const fx4*)(xp + ko);
            xst1 = *(const fx4*)(xp + ko + 16);
            #pragma unroll
            for (int j = 0; j < 4; ++j)
                wst[j] = *(const fx4*)(wsp + ko + j * 4);
        }

        const float* xb_ = &xs[cur][0][0];
        const float* wb_ = &ws[cur][0][0];

        fx4 xv0[8], xv1[8], wv0[4], wv1[4];
        // load group 0
        #pragma unroll
        for (int r = 0; r < 8; ++r)
            xv0[r] = *(const fx4*)(xb_ + (rg*8 + r) * KC + ((0 ^ r) << 2));
        wv0[0] = *(const fx4*)(wb_ + cb0 + ((0 ^ key) << 2));
        wv0[1] = *(const fx4*)(wb_ + cb1 + ((0 ^ key) << 2));
        wv0[2] = *(const fx4*)(wb_ + cb2 + ((0 ^ key) << 2));
        wv0[3] = *(const fx4*)(wb_ + cb3 + ((0 ^ key) << 2));

        #pragma unroll
        for (int g = 0; g < 8; g += 2) {
            // prefetch group g+1
            #pragma unroll
            for (int r = 0; r < 8; ++r)
                xv1[r] = *(const fx4*)(xb_ + (rg*8 + r) * KC + (((g+1) ^ r) << 2));
            wv1[0] = *(const fx4*)(wb_ + cb0 + (((g+1) ^ key) << 2));
            wv1[1] = *(const fx4*)(wb_ + cb1 + (((g+1) ^ key) << 2));
            wv1[2] = *(const fx4*)(wb_ + cb2 + (((g+1) ^ key) << 2));
            wv1[3] = *(const fx4*)(wb_ + cb3 + (((g+1) ^ key) << 2));
            // compute group g
            #pragma unroll
            for (int kk = 0; kk < 4; ++kk)
                #pragma unroll
                for (int r = 0; r < 8; ++r) {
                    acc[r][0] = fmaf(xv0[r][kk], wv0[0][kk], acc[r][0]);
                    acc[r][1] = fmaf(xv0[r][kk], wv0[1][kk], acc[r][1]);
                    acc[r][2] = fmaf(xv0[r][kk], wv0[2][kk], acc[r][2]);
                    acc[r][3] = fmaf(xv0[r][kk], wv0[3][kk], acc[r][3]);
                }
            // prefetch group g+2
            if (g + 2 < 8) {
                #pragma unroll
                for (int r = 0; r < 8; ++r)
                    xv0[r] = *(const fx4*)(xb_ + (rg*8 + r) * KC + (((g+2) ^ r) << 2));
                wv0[0] = *(const fx4*)(wb_ + cb0 + (((g+2) ^ key) << 2));
                wv0[1] = *(const fx4*)(wb_ + cb1 + (((g+2) ^ key) << 2));
                wv0[2] = *(const fx4*)(wb_ + cb2 + (((g+2) ^ key) << 2));
                wv0[3] = *(const fx4*)(wb_ + cb3 + (((g+2) ^ key) << 2));
            }
            // compute group g+1
            #pragma unroll
            for (int kk = 0; kk < 4; ++kk)
                #pragma unroll
                for (int r = 0; r < 8; ++r) {
                    acc[r][0] = fmaf(xv1[r][kk], wv1[0][kk], acc[r][0]);
                    acc[r][1] = fmaf(xv1[r][kk], wv1[1][kk], acc[r][1]);
                    acc[r][2] = fmaf(xv1[r][kk], wv1[2][kk], acc[r][2]);
                    acc[r][3] = fmaf(xv1[r][kk], wv1[3][kk], acc[r][3]);
                }
        }
        __syncthreads();
    }

    // ---- epilogue: LDS-free. h, per-row top-2 via 32-lane butterfly, store ----
    const int e0 = 2 * cg, e1 = 2 * cg + 1;
    const float gb0 = gb[e0], gb1 = gb[e1];
    const float nb0 = nb[e0], nb1 = nb[e1];

    #pragma unroll
    for (int r = 0; r < 8; ++r) {
        const int grow = row0 + rg * 8 + r;
        const float2 ev = *(const float2*)(eps + (size_t)grow * ENUM + e0);

        float nz0 = acc[r][2] + nb0;
        float nz1 = acc[r][3] + nb1;
        float sp0 = fmaxf(nz0, 0.f) + log1pf(expf(-fabsf(nz0)));
        float sp1 = fmaxf(nz1, 0.f) + log1pf(expf(-fabsf(nz1)));
        float h0  = acc[r][0] + gb0 + ev.x * sp0;
        float h1  = acc[r][1] + gb1 + ev.y * sp1;

        float v1, v2; int i1, i2;
        if (h0 >= h1) { v1 = h0; i1 = e0; v2 = h1; i2 = e1; }
        else          { v1 = h1; i1 = e1; v2 = h0; i2 = e0; }

        #pragma unroll
        for (int off = 16; off > 0; off >>= 1) {
            float o1 = __shfl_xor(v1, off);
            int  oi1 = __shfl_xor(i1, off);
            float o2 = __shfl_xor(v2, off);
            int  oi2 = __shfl_xor(i2, off);
            if (o1 > v1) {
                if (o2 > v1) { v2 = o2; i2 = oi2; }
                else         { v2 = v1; i2 = i1;  }
                v1 = o1; i1 = oi1;
            } else if (o1 > v2) {
                v2 = o1; i2 = oi1;
            }
        }
        float e2v = expf(v2 - v1);
        float p1  = 1.f / (1.f + e2v);
        float p2  = e2v * p1;
        float2 o;
        o.x = (e0 == i1) ? p1 : ((e0 == i2) ? p2 : 0.f);
        o.y = (e1 == i1) ? p1 : ((e1 == i2) ? p2 : 0.f);
        *(float2*)(out + (size_t)grow * ENUM + e0) = o;
    }
}

extern "C" void kernel_launch(void* const* d_in, const int* in_sizes, int n_in,
                              void* d_out, int out_size, void* d_ws, size_t ws_size,
                              hipStream_t stream) {
    const float* x   = (const float*)d_in[0];
    const float* eps = (const float*)d_in[1];
    const float* Wg  = (const float*)d_in[2];
    const float* gbp = (const float*)d_in[3];
    const float* Wn  = (const float*)d_in[4];
    const float* nbp = (const float*)d_in[5];
    float* out = (float*)d_out;

    const int M = in_sizes[0] / DDIM;    // B*T = 16384
    dim3 grid(M / TM), block(256);
    hipLaunchKernelGGL(noisy_topk_kernel, grid, block, 0, stream,
                       x, eps, Wg, gbp, Wn, nbp, out);
}

// Round 6
// 133.753 us; speedup vs baseline: 2.3578x; 1.1999x over previous
//
#include <hip/hip_runtime.h>
#include <math.h>

typedef float fx4 __attribute__((ext_vector_type(4)));

#define TM    32      // rows per block
#define TN    128     // 64 gate cols + 64 noise cols
#define KC    32      // K chunk staged in LDS (8 groups of 4 k)
#define DDIM  2048
#define ENUM  64
#define NC    (DDIM / KC)   // 64 chunks

__global__ __launch_bounds__(256, 2)
void noisy_topk_kernel(const float* __restrict__ x,
                       const float* __restrict__ eps,
                       const float* __restrict__ Wg,
                       const float* __restrict__ gb,
                       const float* __restrict__ Wn,
                       const float* __restrict__ nb,
                       float* __restrict__ out)
{
    __shared__ float xs[2][KC][TM];      // 8 KB  [buf][k][row]
    __shared__ float ws[2][KC][TN];      // 32 KB [buf][k][col]
    __shared__ float hbuf[TM][TN + 4];   // 16.9 KB
    __shared__ float pv1[TM][8], pv2[TM][8];
    __shared__ int   pi1[TM][8], pi2[TM][8];
    __shared__ float tp1[TM], tp2[TM];
    __shared__ int   ti1[TM], ti2[TM];

    const int tid  = threadIdx.x;
    const int row0 = blockIdx.x * TM;

    // ---- staging thread mapping (same as R3) ----
    const int xrow = tid & 31;           // row this thread stages
    const int xq   = tid >> 5;           // 0..7 -> k offset xq*4
    const int wc   = tid & 127;          // weight col (0..63 gate, 64..127 noise)
    const int wq   = tid >> 7;           // 0..1 -> k offset wq*16

    const float* xp   = x + (size_t)(row0 + xrow) * DDIM + xq * 4;
    const float* wrow = (wc < ENUM) ? (Wg + (size_t)wc * DDIM)
                                    : (Wn + (size_t)(wc - ENUM) * DDIM);
    const float* wp   = wrow + wq * 16;

    // ---- compute mapping: wave footprint 8 rg x 8 cg (conflict-free broadcasts) ----
    const int rg = (tid >> 3) & 7;               // rows rg*4 .. rg*4+3
    const int cg = (tid & 7) | ((tid >> 6) << 3);// cols cg*4 .. cg*4+3

    float acc[4][4];
    #pragma unroll
    for (int i = 0; i < 4; ++i)
        #pragma unroll
        for (int j = 0; j < 4; ++j) acc[i][j] = 0.f;

    // ---- prologue: stage chunk 0, prefetch chunk 1 ----
    fx4 xr  = *(const fx4*)(xp);
    fx4 wr0 = *(const fx4*)(wp + 0);
    fx4 wr1 = *(const fx4*)(wp + 4);
    fx4 wr2 = *(const fx4*)(wp + 8);
    fx4 wr3 = *(const fx4*)(wp + 12);
    #pragma unroll
    for (int j = 0; j < 4; ++j) xs[0][xq*4 + j][xrow]      = xr[j];
    #pragma unroll
    for (int j = 0; j < 4; ++j) ws[0][wq*16 + j][wc]       = wr0[j];
    #pragma unroll
    for (int j = 0; j < 4; ++j) ws[0][wq*16 + 4 + j][wc]   = wr1[j];
    #pragma unroll
    for (int j = 0; j < 4; ++j) ws[0][wq*16 + 8 + j][wc]   = wr2[j];
    #pragma unroll
    for (int j = 0; j < 4; ++j) ws[0][wq*16 + 12 + j][wc]  = wr3[j];
    xr  = *(const fx4*)(xp + KC);
    wr0 = *(const fx4*)(wp + KC + 0);
    wr1 = *(const fx4*)(wp + KC + 4);
    wr2 = *(const fx4*)(wp + KC + 8);
    wr3 = *(const fx4*)(wp + KC + 12);
    __syncthreads();

    for (int c = 0; c < NC; ++c) {
        const int cur = c & 1;
        const int nxt = cur ^ 1;

        // stage chunk c+1 (regs loaded last iter) into the other buffer
        if (c + 1 < NC) {
            #pragma unroll
            for (int j = 0; j < 4; ++j) xs[nxt][xq*4 + j][xrow]     = xr[j];
            #pragma unroll
            for (int j = 0; j < 4; ++j) ws[nxt][wq*16 + j][wc]      = wr0[j];
            #pragma unroll
            for (int j = 0; j < 4; ++j) ws[nxt][wq*16 + 4 + j][wc]  = wr1[j];
            #pragma unroll
            for (int j = 0; j < 4; ++j) ws[nxt][wq*16 + 8 + j][wc]  = wr2[j];
            #pragma unroll
            for (int j = 0; j < 4; ++j) ws[nxt][wq*16 + 12 + j][wc] = wr3[j];
        }
        // prefetch chunk c+2 from global (latency hidden under compute)
        if (c + 2 < NC) {
            const int ko = (c + 2) * KC;
            xr  = *(const fx4*)(xp + ko);
            wr0 = *(const fx4*)(wp + ko + 0);
            wr1 = *(const fx4*)(wp + ko + 4);
            wr2 = *(const fx4*)(wp + ko + 8);
            wr3 = *(const fx4*)(wp + ko + 12);
        }

        // ---- compute chunk c: 8 groups of 4 k, A/B register ping-pong ----
        const float* xsb = &xs[cur][0][0];
        const float* wsb = &ws[cur][0][0];
        fx4 xA[4], wA[4], xB[4], wB[4];

        #pragma unroll
        for (int kk = 0; kk < 4; ++kk) {
            xA[kk] = *(const fx4*)(xsb + kk * TM + rg * 4);
            wA[kk] = *(const fx4*)(wsb + kk * TN + cg * 4);
        }

        #pragma unroll
        for (int g = 0; g < 8; g += 2) {
            // issue loads for group g+1 into B (covers LDS latency under A's FMAs)
            #pragma unroll
            for (int kk = 0; kk < 4; ++kk) {
                const int kb = (g + 1) * 4 + kk;
                xB[kk] = *(const fx4*)(xsb + kb * TM + rg * 4);
                wB[kk] = *(const fx4*)(wsb + kb * TN + cg * 4);
            }
            // compute group g from A (64 FMA = 128 cyc >= ~120 cyc LDS latency)
            #pragma unroll
            for (int kk = 0; kk < 4; ++kk)
                #pragma unroll
                for (int i = 0; i < 4; ++i)
                    #pragma unroll
                    for (int j = 0; j < 4; ++j)
                        acc[i][j] = fmaf(xA[kk][i], wA[kk][j], acc[i][j]);
            // issue loads for group g+2 into A
            if (g + 2 < 8) {
                #pragma unroll
                for (int kk = 0; kk < 4; ++kk) {
                    const int kb = (g + 2) * 4 + kk;
                    xA[kk] = *(const fx4*)(xsb + kb * TM + rg * 4);
                    wA[kk] = *(const fx4*)(wsb + kb * TN + cg * 4);
                }
            }
            // compute group g+1 from B
            #pragma unroll
            for (int kk = 0; kk < 4; ++kk)
                #pragma unroll
                for (int i = 0; i < 4; ++i)
                    #pragma unroll
                    for (int j = 0; j < 4; ++j)
                        acc[i][j] = fmaf(xB[kk][i], wB[kk][j], acc[i][j]);
        }
        __syncthreads();
    }

    // ---- dump C tile to LDS ----
    #pragma unroll
    for (int i = 0; i < 4; ++i) {
        fx4 o;
        #pragma unroll
        for (int j = 0; j < 4; ++j) o[j] = acc[i][j];
        *(fx4*)&hbuf[rg * 4 + i][cg * 4] = o;
    }
    __syncthreads();

    // ---- epilogue: h = gate + eps*softplus(noise); partial top-2 (8 threads/row) ----
    const int rloc = tid >> 3;   // 0..31
    const int q    = tid & 7;    // expert range q*8 .. q*8+7
    {
        float v1 = -INFINITY, v2 = -INFINITY;
        int   i1 = -1, i2 = -1;
        const float* ep = eps + (size_t)(row0 + rloc) * ENUM + q * 8;
        #pragma unroll
        for (int v = 0; v < 2; ++v) {
            fx4 gv  = *(const fx4*)&hbuf[rloc][q * 8 + v * 4];
            fx4 nv  = *(const fx4*)&hbuf[rloc][ENUM + q * 8 + v * 4];
            fx4 ev  = *(const fx4*)(ep + v * 4);
            fx4 gbv = *(const fx4*)(gb + q * 8 + v * 4);
            fx4 nbv = *(const fx4*)(nb + q * 8 + v * 4);
            #pragma unroll
            for (int j = 0; j < 4; ++j) {
                float nz = nv[j] + nbv[j];
                float sp = fmaxf(nz, 0.f) + log1pf(expf(-fabsf(nz)));
                float h  = gv[j] + gbv[j] + ev[j] * sp;
                int   e  = q * 8 + v * 4 + j;
                if (h > v1)      { v2 = v1; i2 = i1; v1 = h; i1 = e; }
                else if (h > v2) { v2 = h;  i2 = e; }
            }
        }
        pv1[rloc][q] = v1; pv2[rloc][q] = v2;
        pi1[rloc][q] = i1; pi2[rloc][q] = i2;
    }
    __syncthreads();

    // ---- merge partials (1 thread/row), softmax over top-2 ----
    if (tid < TM) {
        float v1 = -INFINITY, v2 = -INFINITY;
        int   i1 = -1, i2 = -1;
        #pragma unroll
        for (int qq = 0; qq < 8; ++qq) {
            float a1 = pv1[tid][qq]; int b1 = pi1[tid][qq];
            float a2 = pv2[tid][qq]; int b2 = pi2[tid][qq];
            if (a1 > v1)      { v2 = v1; i2 = i1; v1 = a1; i1 = b1; }
            else if (a1 > v2) { v2 = a1; i2 = b1; }
            if (a2 > v1)      { v2 = v1; i2 = i1; v1 = a2; i1 = b2; }
            else if (a2 > v2) { v2 = a2; i2 = b2; }
        }
        float e2  = expf(v2 - v1);
        float inv = 1.f / (1.f + e2);
        tp1[tid] = inv;
        tp2[tid] = e2 * inv;
        ti1[tid] = i1; ti2[tid] = i2;
    }
    __syncthreads();

    // ---- coalesced output write ----
    {
        const int   orow = tid >> 3;
        const int   oq   = tid & 7;
        const int   a1 = ti1[orow], a2 = ti2[orow];
        const float p1 = tp1[orow], p2 = tp2[orow];
        float* op = out + (size_t)(row0 + orow) * ENUM + oq * 8;
        #pragma unroll
        for (int v = 0; v < 2; ++v) {
            fx4 o;
            #pragma unroll
            for (int j = 0; j < 4; ++j) {
                int e = oq * 8 + v * 4 + j;
                o[j] = (e == a1) ? p1 : ((e == a2) ? p2 : 0.f);
            }
            *(fx4*)(op + v * 4) = o;
        }
    }
}

extern "C" void kernel_launch(void* const* d_in, const int* in_sizes, int n_in,
                              void* d_out, int out_size, void* d_ws, size_t ws_size,
                              hipStream_t stream) {
    const float* x   = (const float*)d_in[0];
    const float* eps = (const float*)d_in[1];
    const float* Wg  = (const float*)d_in[2];
    const float* gbp = (const float*)d_in[3];
    const float* Wn  = (const float*)d_in[4];
    const float* nbp = (const float*)d_in[5];
    float* out = (float*)d_out;

    const int M = in_sizes[0] / DDIM;    // B*T = 16384
    dim3 grid(M / TM), block(256);
    hipLaunchKernelGGL(noisy_topk_kernel, grid, block, 0, stream,
                       x, eps, Wg, gbp, Wn, nbp, out);
}